// Round 5
// baseline (202.028 us; speedup 1.0000x reference)
//
#include <hip/hip_runtime.h>
#include <math.h>

namespace {

constexpr int kT = 365;
constexpr int kG = 2000;
constexpr int kM = 8;     // ensemble multiplier
constexpr int kF = 15;    // UH length
constexpr float kPrecs = 1e-5f;

// HALF layout (floats): pad[0,60000) | q2[(t*2+h)*kG+g] @60000 | w @1520000
constexpr int kPadH  = kF * 2 * kG;            // 60000
constexpr int kQH    = kPadH;                  // 60000
constexpr int kWH    = kPadH + kT * 2 * kG;    // 1520000
constexpr size_t kNeedH = (size_t)(kWH + kF * kG) * 4;   // 6.2 MB

// FULL layout (floats): pad[0,30000) | q[t*kG+g] @30000 | w @760000
constexpr int kPadF  = kF * kG;                // 30000
constexpr int kQF    = kPadF;
constexpr int kWF    = kPadF + kT * kG;        // 760000

__device__ __forceinline__ float rcpf(float v) { return __builtin_amdgcn_rcpf(v); }

// v += quad_perm-permuted v via DPP (pure VALU, no LDS pipe)
template <int CTRL>
__device__ __forceinline__ float dpp_xadd(float v) {
    int r = __builtin_amdgcn_update_dpp(0, __float_as_int(v), CTRL, 0xF, 0xF, true);
    return v + __int_as_float(r);
}

// param-only derived quantities (computed one pipeline stage ahead); 7 rcp
struct Derived {
    float pctim, kuz, pfree, klzp, klzs;
    float uztwm, uzfwm, lztwm, lzfwpm, lzfwsm;
    float r_uztwm, r_uzfwm, r_lztwm, r_uzsum;
    float pbase, Zp, rexp1;          // demand = pbase + Zp * powv ; Zp = totalm - pbase
    float r_totalm, s23m, r_den, flz_fb;
};

__device__ __forceinline__ Derived make_derived(const float pr[11]) {
#pragma clang fp contract(fast)
    Derived d;
    d.pctim = pr[0];
    const float smax = pr[1] * 1999.f + 1.f;
    const float f1   = pr[2] * 0.99f + 0.005f;
    const float f2   = pr[3] * 0.99f + 0.005f;
    d.kuz            = pr[4];
    const float rexp = pr[5] * 7.f;
    const float f3   = pr[6] * 0.99f + 0.005f;
    const float f4   = pr[7] * 0.99f + 0.005f;
    d.pfree = pr[8]; d.klzp = pr[9]; d.klzs = pr[10];

    d.uztwm  = fmaxf(kPrecs, f1 * smax);
    d.uzfwm  = fmaxf(kPrecs, f2 * (smax - d.uztwm));
    d.lztwm  = fmaxf(kPrecs, f3 * (smax - d.uztwm - d.uzfwm));
    const float rem = smax - d.uztwm - d.uzfwm - d.lztwm;
    d.lzfwpm = fmaxf(kPrecs, f4 * rem);
    d.lzfwsm = fmaxf(kPrecs, (1.f - f4) * rem);

    const float totalm = d.lztwm + d.lzfwpm + d.lzfwsm;
    d.pbase  = d.lzfwpm * d.klzp + d.lzfwsm * d.klzs;
    d.Zp     = totalm - d.pbase;     // == pbase*zperc exactly (algebraic identity)
    d.rexp1  = 1.f + rexp;

    d.r_uztwm  = rcpf(d.uztwm);
    d.r_uzfwm  = rcpf(d.uzfwm);
    d.r_lztwm  = rcpf(d.lztwm);
    d.r_uzsum  = rcpf(d.uztwm + d.uzfwm);

    d.s23m     = d.lzfwpm + d.lzfwsm;
    d.r_totalm = rcpf(totalm);
    d.r_den    = rcpf(d.s23m * totalm);
    d.flz_fb   = d.lzfwpm * rcpf(d.s23m);
    return d;
}

struct PBuf { float pr[11]; float P, Ep; };

// ---------------- kernel A: the sequential scan ----------------
// HALF=true: store per-timestep HALF-sums (quad0/quad1) to q2[(t*2+h)*kG+g]
// HALF=false: full m-reduction in-kernel, store q[t*kG+g]
template <bool HALF>
__global__ __launch_bounds__(64, 1) void sacsma_scan(
    const float* __restrict__ x,           // [T, G, 4]
    const float* __restrict__ params_raw,  // [T, G, 11, M]
    float* __restrict__ qs)                // q region base (t=0)
{
#pragma clang fp contract(fast)
    const int tid = blockIdx.x * 64 + threadIdx.x;
    const int g = tid >> 3;
    const int m = tid & 7;

    constexpr size_t PS = (size_t)kG * 11 * kM;  // param stride per t (floats)
    constexpr size_t XS = (size_t)kG * 4;        // x stride per t

    float uztw = 1e-4f, uzfw = 1e-4f, lztw = 1e-4f, lzfwp = 1e-4f, lzfws = 1e-4f;

    // t=0 params/forcing directly
    const float* p0 = params_raw + (size_t)g * 88 + m;
    const float* x0 = x + (size_t)g * 4;
    float pr0[11];
#pragma unroll
    for (int i = 0; i < 11; ++i) pr0[i] = p0[i * 8];
    Derived d = make_derived(pr0);
    float P = x0[0], Ep = x0[3];

    // runner pointers for the two prefetch buffers
    const float* pA = p0 + PS;        // -> t=1
    const float* pB = p0 + 2 * PS;    // -> t=2
    const float* xA = x0 + XS;
    const float* xB = x0 + 2 * XS;

    PBuf A, B;
#pragma unroll
    for (int i = 0; i < 11; ++i) A.pr[i] = pA[i * 8];
    A.P = xA[0]; A.Ep = xA[3];
    pA += 2 * PS; xA += 2 * XS;       // -> t=3
#pragma unroll
    for (int i = 0; i < 11; ++i) B.pr[i] = pB[i * 8];
    B.P = xB[0]; B.Ep = xB[3];
    pB += 2 * PS; xB += 2 * XS;       // -> t=4

    // output pointer: HALF -> lane handles (t=TB+(m&3), h=m>>2); FULL -> m<4 rows
    float* qp;
    if (HALF) qp = qs + ((size_t)((m & 3) * 2 + (m >> 2))) * kG + g;
    else      qp = qs + (size_t)m * kG + g;

    float q0 = 0.f, q1 = 0.f, q2 = 0.f, q3 = 0.f;

#define FLUX(QREG) do {                                                       \
        const float qdir = d.pctim * P;                                       \
        const float peff = (1.f - d.pctim) * P;                               \
        const float ratio_u1 = uztw * d.r_uztwm;                              \
        const float ratio_u2 = uzfw * d.r_uzfwm;                              \
        const float ru = (ratio_u1 < ratio_u2)                                \
            ? (uzfw * d.uztwm - uztw * d.uzfwm) * d.r_uzsum : 0.f;            \
        const float euztw = fminf(ratio_u1 * Ep, uztw);                       \
        const float twexu = (uztw >= d.uztwm) ? peff : 0.f;                   \
        const float qsur  = (uzfw >= d.uzfwm) ? twexu : 0.f;                  \
        const float qint  = d.kuz * uzfw;                                     \
        const float euzfw = fminf(uzfw, fmaxf(Ep - euztw, 0.f));              \
        const float deficit = fmaxf(d.lztwm - lztw, 0.f)                      \
            + fmaxf(d.lzfwpm - lzfwp, 0.f) + fmaxf(d.lzfwsm - lzfws, 0.f);    \
        const float xrel = deficit * d.r_totalm;                              \
        const float powv = exp2f(d.rexp1 * __log2f(xrel));                    \
        const float demand = d.pbase + d.Zp * powv;                           \
        const float srel = fmaxf(1e-8f, ratio_u2);                            \
        const float pc   = fmaxf(1e-8f, fminf(uzfw, srel * demand));          \
        const float pctw = (1.f - d.pfree) * pc;                              \
        const float pcfw = d.pfree * pc;                                      \
        const float n1 = (d.lzfwpm - lzfwp) * d.lzfwsm;                       \
        const float n2 = (d.lzfwsm - lzfws) * d.lzfwpm;                       \
        const float ns = n1 + n2;                                             \
        const float flz = (ns != 0.f) ? n1 * rcpf(ns) : d.flz_fb;             \
        const float pcfwp = flz * pcfw;                                       \
        const float pcfws = (1.f - flz) * pcfw;                               \
        const float lsum = lzfwp + lzfws;                                     \
        const float ratio_l = lztw * d.r_lztwm;                               \
        const bool  lmask = lztw * d.s23m < lsum * d.lztwm;                   \
        const float nume = (lztw * d.s23m + d.lztwm * lsum) * d.r_den;        \
        const float rlp = lmask ? lzfwp * nume : 0.f;                         \
        const float rls = lmask ? lzfws * nume : 0.f;                         \
        const float elztw = fminf(ratio_l * fmaxf(Ep - euztw - euzfw, 0.f), lztw); \
        const float twexl = (lztw >= d.lztwm) ? pctw : 0.f;                   \
        const float twexlp = flz * twexl;                                     \
        const float twexls = (1.f - flz) * twexl;                             \
        const float qbfp = d.klzp * lzfwp;                                    \
        const float qbfs = d.klzs * lzfws;                                    \
        QREG = qdir + qsur + qint + qbfp + qbfs;                              \
        uztw  = fminf(fmaxf(uztw + peff + ru - euztw - twexu, kPrecs), d.uztwm);   \
        uzfw  = fminf(fmaxf(uzfw + twexu - ru - euzfw - qint - qsur - pc, kPrecs), d.uzfwm); \
        lztw  = fminf(fmaxf(lztw + pctw - twexl + rlp + rls - elztw, kPrecs), d.lztwm);      \
        lzfwp = fminf(fmaxf(lzfwp + pcfwp + twexlp - rlp - qbfp, kPrecs), d.lzfwpm);         \
        lzfws = fminf(fmaxf(lzfws + pcfws + twexls - rls - qbfs, kPrecs), d.lzfwsm);         \
    } while (0)

    // full body: fluxes, then rotate pipeline (consume BUF, reissue from runner)
#define BODY(BUF, PP, XP, QREG) do {                                          \
        FLUX(QREG);                                                           \
        const float _Pn = BUF.P, _En = BUF.Ep;                                \
        const Derived _dn = make_derived(BUF.pr);                             \
        _Pragma("unroll")                                                     \
        for (int _i = 0; _i < 11; ++_i) BUF.pr[_i] = PP[_i * 8];              \
        BUF.P = XP[0]; BUF.Ep = XP[3];                                        \
        PP += 2 * PS; XP += 2 * XS;                                           \
        d = _dn; P = _Pn; Ep = _En;                                           \
    } while (0)

    // no-reissue body (tail)
#define BODY_NI(BUF, QREG) do {                                               \
        FLUX(QREG);                                                           \
        const float _Pn = BUF.P, _En = BUF.Ep;                                \
        const Derived _dn = make_derived(BUF.pr);                             \
        d = _dn; P = _Pn; Ep = _En;                                           \
    } while (0)

#define FLUSH() do {                                                          \
        q0 = dpp_xadd<0xB1>(q0); q1 = dpp_xadd<0xB1>(q1);                     \
        q2 = dpp_xadd<0xB1>(q2); q3 = dpp_xadd<0xB1>(q3);                     \
        q0 = dpp_xadd<0x4E>(q0); q1 = dpp_xadd<0x4E>(q1);                     \
        q2 = dpp_xadd<0x4E>(q2); q3 = dpp_xadd<0x4E>(q3);                     \
        if (HALF) {                                                           \
            const float _v01 = (m & 1) ? q1 : q0;                             \
            const float _v23 = (m & 1) ? q3 : q2;                             \
            const float _v = (m & 2) ? _v23 : _v01;                           \
            qp[0] = _v;                       /* all 8 lanes store */         \
            qp += 8 * kG;                                                     \
        } else {                                                              \
            q0 += __shfl_xor(q0, 4); q1 += __shfl_xor(q1, 4);                 \
            q2 += __shfl_xor(q2, 4); q3 += __shfl_xor(q3, 4);                 \
            const float _v01 = (m & 1) ? q1 : q0;                             \
            const float _v23 = (m & 1) ? q3 : q2;                             \
            const float _v = (m & 2) ? _v23 : _v01;                           \
            if (m < 4) qp[0] = _v;                                            \
            qp += 4 * kG;                                                     \
        }                                                                     \
    } while (0)

    for (int t = 0; t < 357; t += 4) {   // bodies 0..359
        BODY(A, pA, xA, q0);
        BODY(B, pB, xB, q1);
        BODY(A, pA, xA, q2);
        BODY(B, pB, xB, q3);
        FLUSH();
    }
    // tail: bodies 360..364
    BODY(A, pA, xA, q0);     // reissues t=363 (valid)
    BODY(B, pB, xB, q1);     // reissues t=364 (valid)
    BODY_NI(A, q2);          // consumes t=363
    BODY_NI(B, q3);          // consumes t=364
    FLUSH();
    FLUX(q0);                // t=364 (d,P,Ep already rotated in)
    q0 = dpp_xadd<0xB1>(q0);
    q0 = dpp_xadd<0x4E>(q0);
    if (HALF) {
        if ((m & 3) == 0) qp[0] = q0;     // lanes 0,4 -> halves of t=364
    } else {
        q0 += __shfl_xor(q0, 4);
        if (m == 0) qp[0] = q0;
    }

#undef FLUX
#undef BODY
#undef BODY_NI
#undef FLUSH
}

// ---------------- kernel B: gamma UH weights (x0.125 ensemble-mean fold) ----------------
__global__ void uh_weights(const float* __restrict__ conv_params,
                           float* __restrict__ wbuf)   // [15][G]
{
    const int g = blockIdx.x * blockDim.x + threadIdx.x;
    if (g >= kG) return;
    const float aa = fmaxf(conv_params[2 * g] * 2.9f, 0.f) + 0.1f;
    const float th = fmaxf(conv_params[2 * g + 1] * 6.5f, 0.f) + 0.5f;
    const float cw = expf(-lgammaf(aa)) * powf(th, -aa);
    float w[kF];
    float s = 0.f;
#pragma unroll
    for (int k = 0; k < kF; ++k) {
        const float tt = (float)k + 0.5f;
        w[k] = cw * powf(tt, aa - 1.f) * expf(-tt / th);
        s += w[k];
    }
    const float inv = 0.125f / s;   // normalize + fold ensemble mean (q stored as sum)
#pragma unroll
    for (int k = 0; k < kF; ++k) wbuf[k * kG + g] = w[k] * inv;
}

// ---------------- kernel C: causal UH convolution ----------------
template <bool HALF>
__global__ void uh_conv(const float* __restrict__ qbase,  // q region (t=0)
                        const float* __restrict__ wbase,  // [15][G]
                        float* __restrict__ out)          // [T][G]
{
    const int tid = blockIdx.x * blockDim.x + threadIdx.x;
    if (tid >= kT * kG) return;
    const int t = tid / kG;
    const int g = tid - t * kG;
    float y = 0.f;
#pragma unroll
    for (int k = 0; k < kF; ++k) {
        const ptrdiff_t tk = (ptrdiff_t)(t - k);
        float qv;
        if (HALF) qv = qbase[tk * 2 * kG + g] + qbase[tk * 2 * kG + kG + g];
        else      qv = qbase[tk * kG + g];
        y += wbase[k * kG + g] * qv;
    }
    out[(size_t)t * kG + g] = y;
}

}  // namespace

extern "C" void kernel_launch(void* const* d_in, const int* in_sizes, int n_in,
                              void* d_out, int out_size, void* d_ws, size_t ws_size,
                              hipStream_t stream) {
    const float* x           = (const float*)d_in[0];
    // d_in[1] = c_hydro_model — unused by the reference forward
    const float* params_raw  = (const float*)d_in[2];
    const float* conv_params = (const float*)d_in[3];
    float* out = (float*)d_out;
    float* ws  = (float*)d_ws;

    const int nconv = (kT * kG + 255) / 256;
    if (ws_size >= kNeedH) {
        // zero the q pad region (t<0 taps) every call — replays don't re-poison
        (void)hipMemsetAsync(ws, 0, (size_t)kPadH * sizeof(float), stream);
        uh_weights<<<(kG + 255) / 256, 256, 0, stream>>>(conv_params, ws + kWH);
        sacsma_scan<true><<<(kG * kM) / 64, 64, 0, stream>>>(x, params_raw, ws + kQH);
        uh_conv<true><<<nconv, 256, 0, stream>>>(ws + kQH, ws + kWH, out);
    } else {
        (void)hipMemsetAsync(ws, 0, (size_t)kPadF * sizeof(float), stream);
        uh_weights<<<(kG + 255) / 256, 256, 0, stream>>>(conv_params, ws + kWF);
        sacsma_scan<false><<<(kG * kM) / 64, 64, 0, stream>>>(x, params_raw, ws + kQF);
        uh_conv<false><<<nconv, 256, 0, stream>>>(ws + kQF, ws + kWF, out);
    }
}

// Round 6
// 164.426 us; speedup vs baseline: 1.2287x; 1.2287x over previous
//
#include <hip/hip_runtime.h>
#include <math.h>

namespace {

constexpr int kT = 365;
constexpr int kG = 2000;
constexpr int kM = 8;     // ensemble multiplier
constexpr int kF = 15;    // UH length
constexpr float kPrecs = 1e-5f;

// ws float offsets: [0, kF*kG) zero pad | q[T][G] | w[15][G]
constexpr int kQBase = kF * kG;
constexpr int kWBase = (kF + kT) * kG;

__device__ __forceinline__ float rcpf(float v) { return __builtin_amdgcn_rcpf(v); }

// v += quad_perm-permuted v via DPP (pure VALU, no LDS pipe)
template <int CTRL>
__device__ __forceinline__ float dpp_xadd(float v) {
    int r = __builtin_amdgcn_update_dpp(0, __float_as_int(v), CTRL, 0xF, 0xF, true);
    return v + __int_as_float(r);
}

// param-only derived quantities (computed one pipeline stage ahead); 6 rcp + 1 log2
struct Derived {
    float pctim, kuz, pfree, klzp, klzs;
    float uztwm, uzfwm, lztwm, lzfwpm, lzfwsm;
    float r_uztwm, r_uzfwm, r_lztwm, r_uzsum;
    float pbase, Zp, rexp1, c_pow;   // demand = pbase + Zp*powv; powv=exp2(rexp1*log2(def)-c_pow)
    float s23m, r_den, flz_fb;
};

__device__ __forceinline__ Derived make_derived(const float pr[11]) {
#pragma clang fp contract(fast)
    Derived d;
    d.pctim = pr[0];
    const float smax = pr[1] * 1999.f + 1.f;
    const float f1   = pr[2] * 0.99f + 0.005f;
    const float f2   = pr[3] * 0.99f + 0.005f;
    d.kuz            = pr[4];
    const float rexp = pr[5] * 7.f;
    const float f3   = pr[6] * 0.99f + 0.005f;
    const float f4   = pr[7] * 0.99f + 0.005f;
    d.pfree = pr[8]; d.klzp = pr[9]; d.klzs = pr[10];

    d.uztwm  = fmaxf(kPrecs, f1 * smax);
    d.uzfwm  = fmaxf(kPrecs, f2 * (smax - d.uztwm));
    d.lztwm  = fmaxf(kPrecs, f3 * (smax - d.uztwm - d.uzfwm));
    const float rem = smax - d.uztwm - d.uzfwm - d.lztwm;
    d.lzfwpm = fmaxf(kPrecs, f4 * rem);
    d.lzfwsm = fmaxf(kPrecs, (1.f - f4) * rem);

    const float totalm = d.lztwm + d.lzfwpm + d.lzfwsm;
    d.pbase  = d.lzfwpm * d.klzp + d.lzfwsm * d.klzs;
    d.Zp     = totalm - d.pbase;          // == pbase*zperc (exact algebraic identity)
    d.rexp1  = 1.f + rexp;
    d.c_pow  = d.rexp1 * __log2f(totalm);

    d.r_uztwm  = rcpf(d.uztwm);
    d.r_uzfwm  = rcpf(d.uzfwm);
    d.r_lztwm  = rcpf(d.lztwm);
    d.r_uzsum  = rcpf(d.uztwm + d.uzfwm);

    d.s23m     = d.lzfwpm + d.lzfwsm;
    d.r_den    = rcpf(d.s23m * totalm);
    d.flz_fb   = d.lzfwpm * rcpf(d.s23m);
    return d;
}

struct PBuf { float pr[11]; float P, Ep; };

// ---------------- kernel A: the sequential scan ----------------
__global__ __launch_bounds__(64, 1) void sacsma_scan(
    const float* __restrict__ x,           // [T, G, 4]
    const float* __restrict__ params_raw,  // [T, G, 11, M]
    float* __restrict__ qs)                // ws q region: [T][G] (sum over m)
{
#pragma clang fp contract(fast)
#pragma clang fp reassociate(on)
    const int tid = blockIdx.x * 64 + threadIdx.x;
    const int g = tid >> 3;
    const int m = tid & 7;

    const size_t PS = (size_t)kG * 11 * kM;  // param stride per t (floats)
    const float* pp = params_raw + (size_t)g * 88 + m;
    const float4* xp4 = (const float4*)x + g;   // index by t*kG

    float uztw = 1e-4f, uzfw = 1e-4f, lztw = 1e-4f, lzfwp = 1e-4f, lzfws = 1e-4f;

    PBuf A, B;

#define ISSUE(BUF, T3) do {                                              \
        const size_t _po = (size_t)(T3) * PS;                            \
        _Pragma("unroll")                                                \
        for (int _i = 0; _i < 11; ++_i) BUF.pr[_i] = pp[_po + _i * kM];  \
        const float4 _xv = xp4[(size_t)(T3) * kG];                       \
        BUF.P = _xv.x; BUF.Ep = _xv.w;                                   \
    } while (0)

    // prologue: t=0 params -> derived; prefetch t=1 (A) and t=2 (B)
    ISSUE(A, 0);
    Derived d = make_derived(A.pr);
    float P = A.P, Ep = A.Ep;
    ISSUE(A, 1);
    ISSUE(B, 2);

    float q0 = 0.f, q1 = 0.f, q2 = 0.f, q3 = 0.f;

#define FLUX(QREG) do {                                                       \
        const float qdir = d.pctim * P;                                       \
        const float peff = P - qdir;                                          \
        const float ratio_u1 = uztw * d.r_uztwm;                              \
        const float ratio_u2 = uzfw * d.r_uzfwm;                              \
        const float ru = (ratio_u1 < ratio_u2)                                \
            ? (uzfw * d.uztwm - uztw * d.uzfwm) * d.r_uzsum : 0.f;            \
        const float euztw = fminf(ratio_u1 * Ep, uztw);                       \
        const float twexu = (uztw >= d.uztwm) ? peff : 0.f;                   \
        const float qsur  = (uzfw >= d.uzfwm) ? twexu : 0.f;                  \
        const float qint  = d.kuz * uzfw;                                     \
        const float erem  = fmaxf(Ep - euztw, 0.f);                           \
        const float euzfw = fminf(uzfw, erem);                                \
        const float deficit = fmaxf(d.lztwm - lztw, 0.f)                      \
            + fmaxf(d.lzfwpm - lzfwp, 0.f) + fmaxf(d.lzfwsm - lzfws, 0.f);    \
        const float powv = exp2f(d.rexp1 * __log2f(deficit) - d.c_pow);       \
        const float demand = d.pbase + d.Zp * powv;                           \
        const float srel = fmaxf(1e-8f, ratio_u2);                            \
        const float pc   = fmaxf(1e-8f, fminf(uzfw, srel * demand));          \
        const float pcfw = d.pfree * pc;                                      \
        const float pctw = pc - pcfw;                                         \
        const float n1 = (d.lzfwpm - lzfwp) * d.lzfwsm;                       \
        const float n2 = (d.lzfwsm - lzfws) * d.lzfwpm;                       \
        const float ns = n1 + n2;                                             \
        const float flz = (ns != 0.f) ? n1 * rcpf(ns) : d.flz_fb;             \
        const float pcfwp = flz * pcfw;                                       \
        const float pcfws = pcfw - pcfwp;                                     \
        const float lsum = lzfwp + lzfws;                                     \
        const float ratio_l = lztw * d.r_lztwm;                               \
        const bool  lmask = lztw * d.s23m < lsum * d.lztwm;                   \
        const float nume = (lztw * d.s23m + d.lztwm * lsum) * d.r_den;        \
        const float rlp = lmask ? lzfwp * nume : 0.f;                         \
        const float rls = lmask ? lzfws * nume : 0.f;                         \
        const float elztw = fminf(ratio_l * fmaxf(erem - euzfw, 0.f), lztw);  \
        const float twexl = (lztw >= d.lztwm) ? pctw : 0.f;                   \
        const float twexlp = flz * twexl;                                     \
        const float twexls = twexl - twexlp;                                  \
        const float qbfp = d.klzp * lzfwp;                                    \
        const float qbfs = d.klzs * lzfws;                                    \
        QREG = qdir + qsur + qint + qbfp + qbfs;                              \
        uztw  = fminf(fmaxf(uztw + peff + ru - euztw - twexu, kPrecs), d.uztwm);   \
        uzfw  = fminf(fmaxf(uzfw + twexu - ru - euzfw - qint - qsur - pc, kPrecs), d.uzfwm); \
        lztw  = fminf(fmaxf(lztw + pctw - twexl + rlp + rls - elztw, kPrecs), d.lztwm);      \
        lzfwp = fminf(fmaxf(lzfwp + pcfwp + twexlp - rlp - qbfp, kPrecs), d.lzfwpm);         \
        lzfws = fminf(fmaxf(lzfws + pcfws + twexls - rls - qbfs, kPrecs), d.lzfwsm);         \
    } while (0)

#define BODY(T, BUF, QREG) do {                                               \
        FLUX(QREG);                                                           \
        const float _Pn = BUF.P, _En = BUF.Ep;                                \
        const Derived _dn = make_derived(BUF.pr);                             \
        if ((T) + 3 < kT) ISSUE(BUF, (T) + 3);                                \
        d = _dn; P = _Pn; Ep = _En;                                           \
    } while (0)

    // batched m-reduction + store of 4 steps: xor1/xor2 via DPP, xor4 via swizzle
#define FLUSH(TB) do {                                                        \
        q0 = dpp_xadd<0xB1>(q0); q1 = dpp_xadd<0xB1>(q1);                     \
        q2 = dpp_xadd<0xB1>(q2); q3 = dpp_xadd<0xB1>(q3);                     \
        q0 = dpp_xadd<0x4E>(q0); q1 = dpp_xadd<0x4E>(q1);                     \
        q2 = dpp_xadd<0x4E>(q2); q3 = dpp_xadd<0x4E>(q3);                     \
        q0 += __shfl_xor(q0, 4); q1 += __shfl_xor(q1, 4);                     \
        q2 += __shfl_xor(q2, 4); q3 += __shfl_xor(q3, 4);                     \
        const float _v01 = (m & 1) ? q1 : q0;                                 \
        const float _v23 = (m & 1) ? q3 : q2;                                 \
        const float _v = (m & 2) ? _v23 : _v01;                               \
        if (m < 4) qs[(size_t)((TB) + m) * kG + g] = _v;                      \
    } while (0)

    for (int t = 0; t < 357; t += 4) {   // bodies 0..359, issues <= 362
        BODY(t,     A, q0);
        BODY(t + 1, B, q1);
        BODY(t + 2, A, q2);
        BODY(t + 3, B, q3);
        FLUSH(t);
    }
    // tail: bodies 360..364 (issues guarded by the constant-folded (T)+3<kT)
    BODY(360, A, q0);
    BODY(361, B, q1);
    BODY(362, A, q2);
    BODY(363, B, q3);
    FLUSH(360);
    FLUX(q0);   // t=364 (d,P,Ep already rotated in)
    q0 = dpp_xadd<0xB1>(q0);
    q0 = dpp_xadd<0x4E>(q0);
    q0 += __shfl_xor(q0, 4);
    if (m == 0) qs[(size_t)364 * kG + g] = q0;

#undef FLUX
#undef BODY
#undef ISSUE
#undef FLUSH
}

// ---------------- kernel B: gamma UH weights (x0.125 ensemble-mean fold) ----------------
__global__ void uh_weights(const float* __restrict__ conv_params,
                           float* __restrict__ wbuf)   // [15][G]
{
    const int g = blockIdx.x * blockDim.x + threadIdx.x;
    if (g >= kG) return;
    const float aa = fmaxf(conv_params[2 * g] * 2.9f, 0.f) + 0.1f;
    const float th = fmaxf(conv_params[2 * g + 1] * 6.5f, 0.f) + 0.5f;
    const float cw = expf(-lgammaf(aa)) * powf(th, -aa);
    float w[kF];
    float s = 0.f;
#pragma unroll
    for (int k = 0; k < kF; ++k) {
        const float tt = (float)k + 0.5f;
        w[k] = cw * powf(tt, aa - 1.f) * expf(-tt / th);
        s += w[k];
    }
    const float inv = 0.125f / s;   // normalize + fold ensemble mean (q stored as sum)
#pragma unroll
    for (int k = 0; k < kF; ++k) wbuf[k * kG + g] = w[k] * inv;
}

// ---------------- kernel C: causal UH convolution ----------------
__global__ void uh_conv(const float* __restrict__ ws,   // base of scratch
                        float* __restrict__ out)        // [T][G]
{
    const int tid = blockIdx.x * blockDim.x + threadIdx.x;
    if (tid >= kT * kG) return;
    const int t = tid / kG;
    const int g = tid - t * kG;
    const float* q = ws + kQBase;   // q[t] at q[t*kG+g]; t<0 hits the zero pad
    const float* w = ws + kWBase;
    float y = 0.f;
#pragma unroll
    for (int k = 0; k < kF; ++k)
        y += w[k * kG + g] * q[(ptrdiff_t)(t - k) * kG + g];
    out[(size_t)t * kG + g] = y;
}

}  // namespace

extern "C" void kernel_launch(void* const* d_in, const int* in_sizes, int n_in,
                              void* d_out, int out_size, void* d_ws, size_t ws_size,
                              hipStream_t stream) {
    const float* x           = (const float*)d_in[0];
    // d_in[1] = c_hydro_model — unused by the reference forward
    const float* params_raw  = (const float*)d_in[2];
    const float* conv_params = (const float*)d_in[3];
    float* out = (float*)d_out;
    float* ws  = (float*)d_ws;

    // zero the q pad region (t<0 taps) every call — replays don't re-poison
    (void)hipMemsetAsync(ws, 0, (size_t)kQBase * sizeof(float), stream);

    uh_weights<<<(kG + 255) / 256, 256, 0, stream>>>(conv_params, ws + kWBase);
    sacsma_scan<<<(kG * kM) / 64, 64, 0, stream>>>(x, params_raw, ws + kQBase);
    uh_conv<<<(kT * kG + 255) / 256, 256, 0, stream>>>(ws, out);
}

// Round 7
// 155.360 us; speedup vs baseline: 1.3004x; 1.0584x over previous
//
#include <hip/hip_runtime.h>
#include <math.h>

namespace {

constexpr int kT = 365;
constexpr int kG = 2000;
constexpr int kM = 8;     // ensemble multiplier
constexpr int kF = 15;    // UH length
constexpr float kPrecs = 1e-5f;

// ws float offsets: [0, kF*kG) zero pad | q[T][G] | w[15][G]
constexpr int kQBase = kF * kG;
constexpr int kWBase = (kF + kT) * kG;

__device__ __forceinline__ float rcpf(float v) { return __builtin_amdgcn_rcpf(v); }

// v += quad_perm-permuted v via DPP (pure VALU, no LDS pipe)
template <int CTRL>
__device__ __forceinline__ float dpp_xadd(float v) {
    int r = __builtin_amdgcn_update_dpp(0, __float_as_int(v), CTRL, 0xF, 0xF, true);
    return v + __int_as_float(r);
}

// param-only derived quantities (computed one pipeline stage ahead); 6 rcp + 1 log2
struct Derived {
    float pctim, kuz, pfree, klzp, klzs;
    float uztwm, uzfwm, lztwm, lzfwpm, lzfwsm;
    float r_uztwm, r_uzfwm, r_lztwm, r_uzsum;
    float pbase, Zp, rexp1, c_pow;   // demand = pbase + Zp*powv; powv=exp2(rexp1*log2(def)-c_pow)
    float s23m, r_den, flz_fb;
};

__device__ __forceinline__ Derived make_derived(const float pr[11]) {
#pragma clang fp contract(fast)
    Derived d;
    d.pctim = pr[0];
    const float smax = pr[1] * 1999.f + 1.f;
    const float f1   = pr[2] * 0.99f + 0.005f;
    const float f2   = pr[3] * 0.99f + 0.005f;
    d.kuz            = pr[4];
    const float rexp = pr[5] * 7.f;
    const float f3   = pr[6] * 0.99f + 0.005f;
    const float f4   = pr[7] * 0.99f + 0.005f;
    d.pfree = pr[8]; d.klzp = pr[9]; d.klzs = pr[10];

    d.uztwm  = fmaxf(kPrecs, f1 * smax);
    d.uzfwm  = fmaxf(kPrecs, f2 * (smax - d.uztwm));
    d.lztwm  = fmaxf(kPrecs, f3 * (smax - d.uztwm - d.uzfwm));
    const float rem = smax - d.uztwm - d.uzfwm - d.lztwm;
    d.lzfwpm = fmaxf(kPrecs, f4 * rem);
    d.lzfwsm = fmaxf(kPrecs, (1.f - f4) * rem);

    const float totalm = d.lztwm + d.lzfwpm + d.lzfwsm;
    d.pbase  = d.lzfwpm * d.klzp + d.lzfwsm * d.klzs;
    d.Zp     = totalm - d.pbase;          // == pbase*zperc (exact algebraic identity)
    d.rexp1  = 1.f + rexp;
    d.c_pow  = d.rexp1 * __log2f(totalm);

    d.r_uztwm  = rcpf(d.uztwm);
    d.r_uzfwm  = rcpf(d.uzfwm);
    d.r_lztwm  = rcpf(d.lztwm);
    d.r_uzsum  = rcpf(d.uztwm + d.uzfwm);

    d.s23m     = d.lzfwpm + d.lzfwsm;
    d.r_den    = rcpf(d.s23m * totalm);
    d.flz_fb   = d.lzfwpm * rcpf(d.s23m);
    return d;
}

struct PBuf { float pr[11]; float P, Ep; };

// ---------------- kernel A: the sequential scan ----------------
__global__ __launch_bounds__(64, 1) void sacsma_scan(
    const float* __restrict__ x,           // [T, G, 4]
    const float* __restrict__ params_raw,  // [T, G, 11, M]
    float* __restrict__ qs)                // ws q region: [T][G] (sum over m)
{
#pragma clang fp contract(fast)
#pragma clang fp reassociate(on)
    const int tid = blockIdx.x * 64 + threadIdx.x;
    const int g = tid >> 3;
    const int m = tid & 7;

    const size_t PS = (size_t)kG * 11 * kM;  // param stride per t (floats)
    const float* pp = params_raw + (size_t)g * 88 + m;
    const float4* xp4 = (const float4*)x + g;   // index by t*kG

    float uztw = 1e-4f, uzfw = 1e-4f, lztw = 1e-4f, lzfwp = 1e-4f, lzfws = 1e-4f;

    PBuf A, B, C, D;

#define ISSUE(BUF, T3) do {                                              \
        const size_t _po = (size_t)(T3) * PS;                            \
        _Pragma("unroll")                                                \
        for (int _i = 0; _i < 11; ++_i) BUF.pr[_i] = pp[_po + _i * kM];  \
        const float4 _xv = xp4[(size_t)(T3) * kG];                       \
        BUF.P = _xv.x; BUF.Ep = _xv.w;                                   \
    } while (0)

    // prologue: t=0 params -> d0; prefetch t=1..4 into A..D (distance-4 pipeline)
    float pr0[11];
#pragma unroll
    for (int i = 0; i < 11; ++i) pr0[i] = pp[i * kM];
    const float4 xv0 = xp4[0];
    ISSUE(A, 1);
    ISSUE(B, 2);
    ISSUE(C, 3);
    ISSUE(D, 4);
    Derived d0 = make_derived(pr0);
    Derived d1;
    float P = xv0.x, Ep = xv0.w;

    float q0 = 0.f, q1 = 0.f, q2 = 0.f, q3 = 0.f;

#define FLUX(DD, QREG) do {                                                   \
        const float qdir = DD.pctim * P;                                      \
        const float peff = P - qdir;                                          \
        const float ratio_u1 = uztw * DD.r_uztwm;                             \
        const float ratio_u2 = uzfw * DD.r_uzfwm;                             \
        const float ru = (ratio_u1 < ratio_u2)                                \
            ? (uzfw * DD.uztwm - uztw * DD.uzfwm) * DD.r_uzsum : 0.f;         \
        const float euztw = fminf(ratio_u1 * Ep, uztw);                       \
        const float twexu = (uztw >= DD.uztwm) ? peff : 0.f;                  \
        const float qsur  = (uzfw >= DD.uzfwm) ? twexu : 0.f;                 \
        const float qint  = DD.kuz * uzfw;                                    \
        const float erem  = fmaxf(Ep - euztw, 0.f);                           \
        const float euzfw = fminf(uzfw, erem);                                \
        const float deficit = fmaxf(DD.lztwm - lztw, 0.f)                     \
            + fmaxf(DD.lzfwpm - lzfwp, 0.f) + fmaxf(DD.lzfwsm - lzfws, 0.f);  \
        const float powv = exp2f(DD.rexp1 * __log2f(deficit) - DD.c_pow);     \
        const float demand = DD.pbase + DD.Zp * powv;                         \
        const float srel = fmaxf(1e-8f, ratio_u2);                            \
        const float pc   = fmaxf(1e-8f, fminf(uzfw, srel * demand));          \
        const float pcfw = DD.pfree * pc;                                     \
        const float pctw = pc - pcfw;                                         \
        const float n1 = (DD.lzfwpm - lzfwp) * DD.lzfwsm;                     \
        const float n2 = (DD.lzfwsm - lzfws) * DD.lzfwpm;                     \
        const float ns = n1 + n2;                                             \
        const float flz = (ns != 0.f) ? n1 * rcpf(ns) : DD.flz_fb;            \
        const float pcfwp = flz * pcfw;                                       \
        const float pcfws = pcfw - pcfwp;                                     \
        const float lsum = lzfwp + lzfws;                                     \
        const float ratio_l = lztw * DD.r_lztwm;                              \
        const bool  lmask = lztw * DD.s23m < lsum * DD.lztwm;                 \
        const float nume = (lztw * DD.s23m + DD.lztwm * lsum) * DD.r_den;     \
        const float rlp = lmask ? lzfwp * nume : 0.f;                         \
        const float rls = lmask ? lzfws * nume : 0.f;                         \
        const float elztw = fminf(ratio_l * fmaxf(erem - euzfw, 0.f), lztw);  \
        const float twexl = (lztw >= DD.lztwm) ? pctw : 0.f;                  \
        const float twexlp = flz * twexl;                                     \
        const float twexls = twexl - twexlp;                                  \
        const float qbfp = DD.klzp * lzfwp;                                   \
        const float qbfs = DD.klzs * lzfws;                                   \
        QREG = qdir + qsur + qint + qbfp + qbfs;                              \
        uztw  = fminf(fmaxf(uztw + peff + ru - euztw - twexu, kPrecs), DD.uztwm);   \
        uzfw  = fminf(fmaxf(uzfw + twexu - ru - euzfw - qint - qsur - pc, kPrecs), DD.uzfwm); \
        lztw  = fminf(fmaxf(lztw + pctw - twexl + rlp + rls - elztw, kPrecs), DD.lztwm);      \
        lzfwp = fminf(fmaxf(lzfwp + pcfwp + twexlp - rlp - qbfp, kPrecs), DD.lzfwpm);         \
        lzfws = fminf(fmaxf(lzfws + pcfws + twexls - rls - qbfs, kPrecs), DD.lzfwsm);         \
    } while (0)

    // body: FLUX with DCUR, build DNXT from BUF (t+1 params), rotate P/Ep, reissue BUF <- t+5
#define BODY(T, DCUR, DNXT, BUF, QREG) do {                                   \
        FLUX(DCUR, QREG);                                                     \
        DNXT = make_derived(BUF.pr);                                          \
        P = BUF.P; Ep = BUF.Ep;                                               \
        ISSUE(BUF, (T) + 5);   /* main loop: (T)+5 <= 364 always valid */     \
    } while (0)

    // tail body: no reissue
#define BODY_NR(DCUR, DNXT, BUF, QREG) do {                                   \
        FLUX(DCUR, QREG);                                                     \
        DNXT = make_derived(BUF.pr);                                          \
        P = BUF.P; Ep = BUF.Ep;                                               \
    } while (0)

    // batched m-reduction + store of 4 steps: xor1/xor2 via DPP, xor4 via swizzle
#define FLUSH(TB) do {                                                        \
        q0 = dpp_xadd<0xB1>(q0); q1 = dpp_xadd<0xB1>(q1);                     \
        q2 = dpp_xadd<0xB1>(q2); q3 = dpp_xadd<0xB1>(q3);                     \
        q0 = dpp_xadd<0x4E>(q0); q1 = dpp_xadd<0x4E>(q1);                     \
        q2 = dpp_xadd<0x4E>(q2); q3 = dpp_xadd<0x4E>(q3);                     \
        q0 += __shfl_xor(q0, 4); q1 += __shfl_xor(q1, 4);                     \
        q2 += __shfl_xor(q2, 4); q3 += __shfl_xor(q3, 4);                     \
        const float _v01 = (m & 1) ? q1 : q0;                                 \
        const float _v23 = (m & 1) ? q3 : q2;                                 \
        const float _v = (m & 2) ? _v23 : _v01;                               \
        if (m < 4) qs[(size_t)((TB) + m) * kG + g] = _v;                      \
    } while (0)

    for (int t = 0; t < 360; t += 4) {   // bodies 0..359; reissues reach t=364 max
        BODY(t,     d0, d1, A, q0);
        BODY(t + 1, d1, d0, B, q1);
        BODY(t + 2, d0, d1, C, q2);
        BODY(t + 3, d1, d0, D, q3);
        FLUSH(t);
    }
    // tail: bodies 360..364; buffers hold A:361 B:362 C:363 D:364
    BODY_NR(d0, d1, A, q0);
    BODY_NR(d1, d0, B, q1);
    BODY_NR(d0, d1, C, q2);
    BODY_NR(d1, d0, D, q3);
    FLUSH(360);
    FLUX(d0, q0);   // t=364 (even -> d0)
    q0 = dpp_xadd<0xB1>(q0);
    q0 = dpp_xadd<0x4E>(q0);
    q0 += __shfl_xor(q0, 4);
    if (m == 0) qs[(size_t)364 * kG + g] = q0;

#undef FLUX
#undef BODY
#undef BODY_NR
#undef ISSUE
#undef FLUSH
}

// ---------------- kernel B: gamma UH weights (x0.125 ensemble-mean fold) ----------------
__global__ void uh_weights(const float* __restrict__ conv_params,
                           float* __restrict__ wbuf)   // [15][G]
{
    const int g = blockIdx.x * blockDim.x + threadIdx.x;
    if (g >= kG) return;
    const float aa = fmaxf(conv_params[2 * g] * 2.9f, 0.f) + 0.1f;
    const float th = fmaxf(conv_params[2 * g + 1] * 6.5f, 0.f) + 0.5f;
    const float cw = expf(-lgammaf(aa)) * powf(th, -aa);
    float w[kF];
    float s = 0.f;
#pragma unroll
    for (int k = 0; k < kF; ++k) {
        const float tt = (float)k + 0.5f;
        w[k] = cw * powf(tt, aa - 1.f) * expf(-tt / th);
        s += w[k];
    }
    const float inv = 0.125f / s;   // normalize + fold ensemble mean (q stored as sum)
#pragma unroll
    for (int k = 0; k < kF; ++k) wbuf[k * kG + g] = w[k] * inv;
}

// ---------------- kernel C: causal UH convolution ----------------
__global__ void uh_conv(const float* __restrict__ ws,   // base of scratch
                        float* __restrict__ out)        // [T][G]
{
    const int tid = blockIdx.x * blockDim.x + threadIdx.x;
    if (tid >= kT * kG) return;
    const int t = tid / kG;
    const int g = tid - t * kG;
    const float* q = ws + kQBase;   // q[t] at q[t*kG+g]; t<0 hits the zero pad
    const float* w = ws + kWBase;
    float y = 0.f;
#pragma unroll
    for (int k = 0; k < kF; ++k)
        y += w[k * kG + g] * q[(ptrdiff_t)(t - k) * kG + g];
    out[(size_t)t * kG + g] = y;
}

}  // namespace

extern "C" void kernel_launch(void* const* d_in, const int* in_sizes, int n_in,
                              void* d_out, int out_size, void* d_ws, size_t ws_size,
                              hipStream_t stream) {
    const float* x           = (const float*)d_in[0];
    // d_in[1] = c_hydro_model — unused by the reference forward
    const float* params_raw  = (const float*)d_in[2];
    const float* conv_params = (const float*)d_in[3];
    float* out = (float*)d_out;
    float* ws  = (float*)d_ws;

    // zero the q pad region (t<0 taps) every call — replays don't re-poison
    (void)hipMemsetAsync(ws, 0, (size_t)kQBase * sizeof(float), stream);

    uh_weights<<<(kG + 255) / 256, 256, 0, stream>>>(conv_params, ws + kWBase);
    sacsma_scan<<<(kG * kM) / 64, 64, 0, stream>>>(x, params_raw, ws + kQBase);
    uh_conv<<<(kT * kG + 255) / 256, 256, 0, stream>>>(ws, out);
}